// Round 1
// baseline (1524.111 us; speedup 1.0000x reference)
//
#include <hip/hip_runtime.h>
#include <math.h>

#define Bsz 512
#define TT 8
#define Dn 2048
#define DIN 512
#define Mh 16
#define Hh 4
#define Pn 512
#define DOUT 512
#define BD (Bsz*Dn)   // 1048576 floats = 4MB

// ---------------- generic fp32 tiled GEMM: C = A@B + bias(row-broadcast) ----
__global__ __launch_bounds__(256)
void gemm_bias_kernel(const float* __restrict__ A, const float* __restrict__ Bm,
                      const float* __restrict__ bias, float* __restrict__ C,
                      int M, int N, int K) {
  __shared__ float As[32][64];
  __shared__ float Bs[32][64];
  const int tid = threadIdx.x;
  const int tx = tid & 15, ty = tid >> 4;
  const int bm = blockIdx.x * 64, bn = blockIdx.y * 64;
  float acc[4][4] = {};
  for (int k0 = 0; k0 < K; k0 += 32) {
#pragma unroll
    for (int l0 = 0; l0 < 2; ++l0) {
      int l = tid + l0 * 256;
      int r = l >> 3, c4 = (l & 7) * 4;
      float4 v = *(const float4*)(A + (size_t)(bm + r) * K + k0 + c4);
      As[c4 + 0][r] = v.x; As[c4 + 1][r] = v.y; As[c4 + 2][r] = v.z; As[c4 + 3][r] = v.w;
      int rb = l >> 4, cb4 = (l & 15) * 4;
      *(float4*)&Bs[rb][cb4] = *(const float4*)(Bm + (size_t)(k0 + rb) * N + bn + cb4);
    }
    __syncthreads();
#pragma unroll
    for (int kk = 0; kk < 32; ++kk) {
      float a[4], b[4];
      *(float4*)a = *(const float4*)&As[kk][ty * 4];
      *(float4*)b = *(const float4*)&Bs[kk][tx * 4];
#pragma unroll
      for (int i = 0; i < 4; ++i)
#pragma unroll
        for (int j = 0; j < 4; ++j)
          acc[i][j] = fmaf(a[i], b[j], acc[i][j]);
    }
    __syncthreads();
  }
  const int col = bn + tx * 4;
  float4 bv = *(const float4*)(bias + col);
#pragma unroll
  for (int i = 0; i < 4; ++i) {
    int row = bm + ty * 4 + i;
    float4 o;
    o.x = acc[i][0] + bv.x; o.y = acc[i][1] + bv.y;
    o.z = acc[i][2] + bv.z; o.w = acc[i][3] + bv.w;
    *(float4*)(C + (size_t)row * N + col) = o;
  }
}

// ---------------- q = z0 @ W_syn_top  (matvec, D x D) ----------------------
__global__ __launch_bounds__(256)
void matvec_q_kernel(const float* __restrict__ z0, const float* __restrict__ W,
                     float* __restrict__ q) {
  __shared__ float red[16][17];
  const int tid = threadIdx.x;
  const int c = tid & 15, strip = tid >> 4;
  const int col = blockIdx.x * 16 + c;
  float acc = 0.f;
  for (int k = strip; k < Dn; k += 16)
    acc = fmaf(z0[k], W[(size_t)k * Dn + col], acc);
  red[strip][c] = acc;
  __syncthreads();
  if (strip == 0) {
    float s = 0.f;
#pragma unroll
    for (int i2 = 0; i2 < 16; ++i2) s += red[i2][c];
    q[col] = s;
  }
}

// ---- tick kernel: pre = (tau==0 ? base+q : z@Wtop + base); fused NLM -> z --
__global__ __launch_bounds__(256)
void tick_kernel(const float* __restrict__ zin, const float* __restrict__ Wtop,
                 const float* __restrict__ base, const float* __restrict__ q,
                 const float* __restrict__ hist, float* __restrict__ histout,
                 const float* __restrict__ w1, const float* __restrict__ b1,
                 const float* __restrict__ w2, const float* __restrict__ b2,
                 float* __restrict__ zout, int tau) {
  __shared__ float As[32][64];
  __shared__ float Bs[32][64];
  const int tid = threadIdx.x;
  const int tx = tid & 15, ty = tid >> 4;
  const int bm = blockIdx.x * 64, bn = blockIdx.y * 64;
  float acc[4][4] = {};
  if (tau > 0) {
    for (int k0 = 0; k0 < Dn; k0 += 32) {
#pragma unroll
      for (int l0 = 0; l0 < 2; ++l0) {
        int l = tid + l0 * 256;
        int r = l >> 3, c4 = (l & 7) * 4;
        float4 v = *(const float4*)(zin + (size_t)(bm + r) * Dn + k0 + c4);
        As[c4 + 0][r] = v.x; As[c4 + 1][r] = v.y; As[c4 + 2][r] = v.z; As[c4 + 3][r] = v.w;
        int rb = l >> 4, cb4 = (l & 15) * 4;
        *(float4*)&Bs[rb][cb4] = *(const float4*)(Wtop + (size_t)(k0 + rb) * Dn + bn + cb4);
      }
      __syncthreads();
#pragma unroll
      for (int kk = 0; kk < 32; ++kk) {
        float a[4], b[4];
        *(float4*)a = *(const float4*)&As[kk][ty * 4];
        *(float4*)b = *(const float4*)&Bs[kk][tx * 4];
#pragma unroll
        for (int i = 0; i < 4; ++i)
#pragma unroll
          for (int j = 0; j < 4; ++j)
            acc[i][j] = fmaf(a[i], b[j], acc[i][j]);
      }
      __syncthreads();
    }
  }
  const int col = bn + tx * 4;
  // column-dependent NLM constants
  float4 b2v = *(const float4*)(b2 + col);
  float4 w2v[Hh], b1v[Hh];
#pragma unroll
  for (int hh = 0; hh < Hh; ++hh) {
    w2v[hh] = *(const float4*)(w2 + (size_t)hh * Dn + col);
    b1v[hh] = *(const float4*)(b1 + (size_t)hh * Dn + col);
  }
#pragma unroll
  for (int i = 0; i < 4; ++i) {
    const int row = bm + ty * 4 + i;
    float4 bs = *(const float4*)(base + (size_t)row * Dn + col);
    float4 pre;
    if (tau == 0) {
      float4 qv = *(const float4*)(q + col);
      pre.x = bs.x + qv.x; pre.y = bs.y + qv.y;
      pre.z = bs.z + qv.z; pre.w = bs.w + qv.w;
    } else {
      pre.x = acc[i][0] + bs.x; pre.y = acc[i][1] + bs.y;
      pre.z = acc[i][2] + bs.z; pre.w = acc[i][3] + bs.w;
    }
    *(float4*)(histout + (size_t)row * Dn + col) = pre;
    // NLM: h[hh] = b1 + sum_{s<=tau} pre_s * w1[15-tau+s][hh]; z = b2 + sum relu(h)*w2
    float4 h[Hh];
#pragma unroll
    for (int hh = 0; hh < Hh; ++hh) h[hh] = b1v[hh];
    for (int s = 0; s <= tau; ++s) {
      float4 ps;
      if (s == tau) ps = pre;
      else ps = *(const float4*)(hist + (size_t)s * BD + (size_t)row * Dn + col);
      const int m = 15 - tau + s;
#pragma unroll
      for (int hh = 0; hh < Hh; ++hh) {
        float4 wv = *(const float4*)(w1 + (size_t)(m * Hh + hh) * Dn + col);
        h[hh].x = fmaf(ps.x, wv.x, h[hh].x);
        h[hh].y = fmaf(ps.y, wv.y, h[hh].y);
        h[hh].z = fmaf(ps.z, wv.z, h[hh].z);
        h[hh].w = fmaf(ps.w, wv.w, h[hh].w);
      }
    }
    float4 zv = b2v;
#pragma unroll
    for (int hh = 0; hh < Hh; ++hh) {
      zv.x = fmaf(fmaxf(h[hh].x, 0.f), w2v[hh].x, zv.x);
      zv.y = fmaf(fmaxf(h[hh].y, 0.f), w2v[hh].y, zv.y);
      zv.z = fmaf(fmaxf(h[hh].z, 0.f), w2v[hh].z, zv.z);
      zv.w = fmaf(fmaxf(h[hh].w, 0.f), w2v[hh].w, zv.w);
    }
    *(float4*)(zout + (size_t)row * Dn + col) = zv;
  }
}

// ---- sync + output GEMM: S_new = S_old*r + z_i z_j; out_t = S_new@W + b ----
__global__ __launch_bounds__(256)
void sync_out_kernel(const float* __restrict__ z, const float* __restrict__ Sold,
                     float* __restrict__ Snew, const float* __restrict__ decay,
                     const int* __restrict__ pairs, const float* __restrict__ W,
                     const float* __restrict__ bias, float* __restrict__ out,
                     int t, int first) {
  __shared__ float Slds[16][Pn];   // 32KB
  __shared__ float rl[Pn];         // 2KB
  __shared__ float Ws[32][128];    // 16KB
  const int tid = threadIdx.x;
  const int brow = blockIdx.x * 16;
  const int cb = blockIdx.y * 128;
  for (int p = tid; p < Pn; p += 256) rl[p] = expf(-fabsf(decay[p]));
  __syncthreads();
  for (int idx = tid; idx < 16 * Pn; idx += 256) {
    int rr = idx >> 9, p = idx & (Pn - 1);
    int row = brow + rr;
    int i = pairs[2 * p], j = pairs[2 * p + 1];
    float v = z[(size_t)row * Dn + i] * z[(size_t)row * Dn + j];
    if (!first) v = fmaf(Sold[(size_t)row * Pn + p], rl[p], v);
    Slds[rr][p] = v;
    if (blockIdx.y == 0) Snew[(size_t)row * Pn + p] = v;
  }
  __syncthreads();
  const int tx = tid & 31, ty = tid >> 5;
  float acc[2][4] = {};
  for (int k0 = 0; k0 < Pn; k0 += 32) {
#pragma unroll
    for (int l0 = 0; l0 < 4; ++l0) {
      int l = tid + l0 * 256;
      int r = l >> 5, c4 = (l & 31) * 4;
      *(float4*)&Ws[r][c4] = *(const float4*)(W + (size_t)(k0 + r) * DOUT + cb + c4);
    }
    __syncthreads();
#pragma unroll
    for (int kk = 0; kk < 32; ++kk) {
      float wv[4];
      *(float4*)wv = *(const float4*)&Ws[kk][tx * 4];
      float s0 = Slds[ty][k0 + kk];
      float s1 = Slds[ty + 8][k0 + kk];
#pragma unroll
      for (int j = 0; j < 4; ++j) {
        acc[0][j] = fmaf(s0, wv[j], acc[0][j]);
        acc[1][j] = fmaf(s1, wv[j], acc[1][j]);
      }
    }
    __syncthreads();
  }
  const int col = cb + tx * 4;
  float4 bv = *(const float4*)(bias + col);
#pragma unroll
  for (int r2 = 0; r2 < 2; ++r2) {
    int row = brow + ty + r2 * 8;
    float4 o;
    o.x = acc[r2][0] + bv.x; o.y = acc[r2][1] + bv.y;
    o.z = acc[r2][2] + bv.z; o.w = acc[r2][3] + bv.w;
    *(float4*)(out + (size_t)row * (TT * DOUT) + (size_t)t * DOUT + col) = o;
  }
}

extern "C" void kernel_launch(void* const* d_in, const int* in_sizes, int n_in,
                              void* d_out, int out_size, void* d_ws, size_t ws_size,
                              hipStream_t stream) {
  const float* x      = (const float*)d_in[0];
  const float* W_in   = (const float*)d_in[1];
  const float* b_in   = (const float*)d_in[2];
  const float* z0     = (const float*)d_in[3];
  const float* W_syn  = (const float*)d_in[4];
  const float* b_syn  = (const float*)d_in[5];
  const float* w1     = (const float*)d_in[6];
  const float* b1     = (const float*)d_in[7];
  const float* w2     = (const float*)d_in[8];
  const float* b2     = (const float*)d_in[9];
  const float* decay_out = (const float*)d_in[10];
  const float* decay_act = (const float*)d_in[11];
  const float* W_out  = (const float*)d_in[12];
  const float* b_out  = (const float*)d_in[13];
  const float* W_act  = (const float*)d_in[14];
  const float* b_act  = (const float*)d_in[15];
  const int* pairs_out = (const int*)d_in[16];
  const int* pairs_act = (const int*)d_in[17];

  float* ws    = (float*)d_ws;
  float* feats = ws;                         // B*D
  float* base  = ws + (size_t)BD;            // B*D
  float* q     = ws + 2 * (size_t)BD;        // D (padded to 4096)
  float* zbuf  = ws + 2 * (size_t)BD + 4096; // 2 * B*D ping-pong
  float* hist  = zbuf + 2 * (size_t)BD;      // 8 * B*D
  float* Sbuf  = hist + 8 * (size_t)BD;      // 4 * B*P  [ping][sel]

  float* outy = (float*)d_out;
  float* outq = outy + (size_t)Bsz * TT * DOUT;

  dim3 blk(256);
  // feats = x @ W_in + b_in
  gemm_bias_kernel<<<dim3(Bsz / 64, Dn / 64), blk, 0, stream>>>(x, W_in, b_in, feats, Bsz, Dn, DIN);
  // base = feats @ W_syn[D:,:] + b_syn   (tick-invariant half of the synapse GEMM)
  gemm_bias_kernel<<<dim3(Bsz / 64, Dn / 64), blk, 0, stream>>>(feats, W_syn + (size_t)Dn * Dn, b_syn, base, Bsz, Dn, Dn);
  // q = z0 @ W_syn[:D,:]   (tick-0 z is broadcast z0)
  matvec_q_kernel<<<dim3(Dn / 16), blk, 0, stream>>>(z0, W_syn, q);

  for (int tau = 0; tau < TT; ++tau) {
    const float* zi = zbuf + (size_t)(tau & 1) * BD;
    float* zo = zbuf + (size_t)((tau + 1) & 1) * BD;
    tick_kernel<<<dim3(Bsz / 64, Dn / 64), blk, 0, stream>>>(
        zi, W_syn, base, q, hist, hist + (size_t)tau * BD,
        w1, b1, w2, b2, zo, tau);
    const int pi = tau & 1, po = (tau + 1) & 1;
    sync_out_kernel<<<dim3(Bsz / 16, DOUT / 128), blk, 0, stream>>>(
        zo, Sbuf + (size_t)(pi * 2 + 0) * Bsz * Pn, Sbuf + (size_t)(po * 2 + 0) * Bsz * Pn,
        decay_out, pairs_out, W_out, b_out, outy, tau, tau == 0);
    sync_out_kernel<<<dim3(Bsz / 16, DOUT / 128), blk, 0, stream>>>(
        zo, Sbuf + (size_t)(pi * 2 + 1) * Bsz * Pn, Sbuf + (size_t)(po * 2 + 1) * Bsz * Pn,
        decay_act, pairs_act, W_act, b_act, outq, tau, tau == 0);
  }
}

// Round 3
// 694.239 us; speedup vs baseline: 2.1954x; 2.1954x over previous
//
#include <hip/hip_runtime.h>
#include <math.h>

#define Bsz 512
#define TT 8
#define Dn 2048
#define DIN 512
#define Hh 4
#define Pn 512
#define DOUT 512
#define BD (Bsz*Dn)

typedef __attribute__((ext_vector_type(8))) short s16x8;
typedef __attribute__((ext_vector_type(4))) float f32x4;
typedef __attribute__((ext_vector_type(4))) unsigned short u16x4;

__device__ __forceinline__ unsigned short f2bf(float f) {
  unsigned int u = __float_as_uint(f);
  unsigned int r = (u + 0x7fffu + ((u >> 16) & 1u)) >> 16;
  return (unsigned short)r;
}
__device__ __forceinline__ float bf2f(unsigned short h) {
  return __uint_as_float(((unsigned int)h) << 16);
}
__device__ __forceinline__ void split2(float x, unsigned short& h, unsigned short& l) {
  h = f2bf(x);
  float r = x - bf2f(h);
  l = f2bf(r);
}

// ---------------- shared MFMA GEMM core ----------------
// A (M,K) as Ah/Al bf16 row-major; B as BT h/l (N,K) row-major.
// 64x64 block tile, BK=32, 4 waves of 32x32, double-buffered swizzled LDS.
__device__ __forceinline__ void gemm_core(
    const unsigned short* __restrict__ Ah, const unsigned short* __restrict__ Al,
    const unsigned short* __restrict__ BTh, const unsigned short* __restrict__ BTl,
    int K, long arow0, long brow0,
    unsigned short As[2][64][64], unsigned short Bs[2][64][64],
    f32x4 acc[2][2])
{
  const int tid = threadIdx.x;
  const int row = tid & 63;     // staging row
  const int cs  = tid >> 6;     // staging k-group (== wave id)
  const size_t rA = (size_t)(arow0 + row) * K + cs * 8;
  const size_t rB = (size_t)(brow0 + row) * K + cs * 8;
  const int wH = (cs ^ (row & 7)) * 8;
  const int wL = ((cs + 4) ^ (row & 7)) * 8;

  s16x8 va_h = *(const s16x8*)(Ah + rA);
  s16x8 va_l = *(const s16x8*)(Al + rA);
  s16x8 vb_h = *(const s16x8*)(BTh + rB);
  s16x8 vb_l = *(const s16x8*)(BTl + rB);
  *(s16x8*)&As[0][row][wH] = va_h;
  *(s16x8*)&As[0][row][wL] = va_l;
  *(s16x8*)&Bs[0][row][wH] = vb_h;
  *(s16x8*)&Bs[0][row][wL] = vb_l;
  __syncthreads();

  const int wave = tid >> 6;
  const int wm = (wave & 1) * 32, wn = (wave >> 1) * 32;
  const int lm = tid & 15;
  const int kg = (tid >> 4) & 3;
  int aoH[2], aoL[2], boH[2], boL[2], arr[2], brr[2];
#pragma unroll
  for (int t2 = 0; t2 < 2; ++t2) {
    int r1 = wm + t2 * 16 + lm;
    arr[t2] = r1;
    aoH[t2] = (kg ^ (r1 & 7)) * 8;
    aoL[t2] = ((kg + 4) ^ (r1 & 7)) * 8;
    int r2 = wn + t2 * 16 + lm;
    brr[t2] = r2;
    boH[t2] = (kg ^ (r2 & 7)) * 8;
    boL[t2] = ((kg + 4) ^ (r2 & 7)) * 8;
  }

  const int nk = K >> 5;
  for (int ks = 0; ks < nk; ++ks) {
    const int cur = ks & 1;
    s16x8 na_h, na_l, nb_h, nb_l;
    if (ks + 1 < nk) {
      size_t o = (size_t)(ks + 1) * 32;
      na_h = *(const s16x8*)(Ah + rA + o);
      na_l = *(const s16x8*)(Al + rA + o);
      nb_h = *(const s16x8*)(BTh + rB + o);
      nb_l = *(const s16x8*)(BTl + rB + o);
    }
    s16x8 fa_h[2], fa_l[2], fb_h[2], fb_l[2];
#pragma unroll
    for (int t2 = 0; t2 < 2; ++t2) {
      fa_h[t2] = *(const s16x8*)&As[cur][arr[t2]][aoH[t2]];
      fa_l[t2] = *(const s16x8*)&As[cur][arr[t2]][aoL[t2]];
      fb_h[t2] = *(const s16x8*)&Bs[cur][brr[t2]][boH[t2]];
      fb_l[t2] = *(const s16x8*)&Bs[cur][brr[t2]][boL[t2]];
    }
#pragma unroll
    for (int mt = 0; mt < 2; ++mt)
#pragma unroll
      for (int nt = 0; nt < 2; ++nt) {
        acc[mt][nt] = __builtin_amdgcn_mfma_f32_16x16x32_bf16(fa_h[mt], fb_h[nt], acc[mt][nt], 0, 0, 0);
        acc[mt][nt] = __builtin_amdgcn_mfma_f32_16x16x32_bf16(fa_h[mt], fb_l[nt], acc[mt][nt], 0, 0, 0);
        acc[mt][nt] = __builtin_amdgcn_mfma_f32_16x16x32_bf16(fa_l[mt], fb_h[nt], acc[mt][nt], 0, 0, 0);
      }
    if (ks + 1 < nk) {
      const int nxt = cur ^ 1;
      *(s16x8*)&As[nxt][row][wH] = na_h;
      *(s16x8*)&As[nxt][row][wL] = na_l;
      *(s16x8*)&Bs[nxt][row][wH] = nb_h;
      *(s16x8*)&Bs[nxt][row][wL] = nb_l;
    }
    __syncthreads();
  }
}

// MODE 0: write split bf16 (Ch/Cl). MODE 1: write fp32 C + bias. MODE 2: out scatter (b,t,n) + bias.
template<int MODE>
__global__ __launch_bounds__(256)
void mfma_gemm(const unsigned short* __restrict__ Ah, const unsigned short* __restrict__ Al,
               const unsigned short* __restrict__ BTh, const unsigned short* __restrict__ BTl,
               const float* __restrict__ bias, float* __restrict__ Cf,
               unsigned short* __restrict__ Ch, unsigned short* __restrict__ Cl,
               int M, int N, int K, int gm, int gn)
{
  __shared__ unsigned short As[2][64][64];
  __shared__ unsigned short Bs[2][64][64];
  int bid = blockIdx.x;
  int xcd = bid & 7, w = bid >> 3;
  int bmi = w % gm, bni = xcd * (gn >> 3) + w / gm;
  long bm = (long)bmi * 64, bn = (long)bni * 64;
  f32x4 acc[2][2];
#pragma unroll
  for (int a = 0; a < 2; ++a)
#pragma unroll
    for (int b = 0; b < 2; ++b) acc[a][b] = (f32x4)0.f;
  gemm_core(Ah, Al, BTh, BTl, K, bm, bn, As, Bs, acc);

  const int tid = threadIdx.x, lane = tid & 63, wave = tid >> 6;
  const int wm = (wave & 1) * 32, wn2 = (wave >> 1) * 32;
#pragma unroll
  for (int mt = 0; mt < 2; ++mt)
#pragma unroll
    for (int nt = 0; nt < 2; ++nt) {
      int n = (int)bn + wn2 + nt * 16 + (lane & 15);
      long r0 = bm + wm + mt * 16 + ((lane >> 4) & 3) * 4;
      float bv = (MODE != 0) ? bias[n] : 0.f;
#pragma unroll
      for (int r = 0; r < 4; ++r) {
        float v = acc[mt][nt][r] + bv;
        long R = r0 + r;
        if (MODE == 0) {
          unsigned short h_, l_; split2(v, h_, l_);
          Ch[R * N + n] = h_; Cl[R * N + n] = l_;
        } else if (MODE == 1) {
          Cf[R * N + n] = v;
        } else {
          long t = R >> 9, b = R & 511;
          Cf[(b * TT + t) * N + n] = v;
        }
      }
    }
}

// ---------------- tick kernel (tau >= 1): GEMM + base + NLM epilogue ----------
template<int TAU>
__global__ __launch_bounds__(256)
void tick_mfma(const unsigned short* __restrict__ zh, const unsigned short* __restrict__ zl,
               const unsigned short* __restrict__ WTh, const unsigned short* __restrict__ WTl,
               const float* __restrict__ basep, const float* __restrict__ hist,
               float* __restrict__ histout,
               const float* __restrict__ w1, const float* __restrict__ b1,
               const float* __restrict__ w2, const float* __restrict__ b2,
               unsigned short* __restrict__ zho, unsigned short* __restrict__ zlo,
               unsigned short* __restrict__ zT)
{
  __shared__ unsigned short As[2][64][64];
  __shared__ unsigned short Bs[2][64][64];
  int bid = blockIdx.x;
  int xcd = bid & 7, w = bid >> 3;
  int bmi = w % 8, bni = xcd * 4 + w / 8;
  long bm = (long)bmi * 64, bn = (long)bni * 64;
  f32x4 acc[2][2];
#pragma unroll
  for (int a = 0; a < 2; ++a)
#pragma unroll
    for (int b = 0; b < 2; ++b) acc[a][b] = (f32x4)0.f;
  gemm_core(zh, zl, WTh, WTl, Dn, bm, bn, As, Bs, acc);

  const int tid = threadIdx.x, lane = tid & 63, wave = tid >> 6;
  const int wm = (wave & 1) * 32, wn2 = (wave >> 1) * 32;
#pragma unroll
  for (int mt = 0; mt < 2; ++mt)
#pragma unroll
    for (int nt = 0; nt < 2; ++nt) {
      const int d = (int)bn + wn2 + nt * 16 + (lane & 15);
      const int b0 = (int)bm + wm + mt * 16 + ((lane >> 4) & 3) * 4;
      float w2v[Hh], b1v[Hh];
#pragma unroll
      for (int hh = 0; hh < Hh; ++hh) {
        w2v[hh] = w2[hh * Dn + d];
        b1v[hh] = b1[hh * Dn + d];
      }
      const float b2v = b2[d];
      float pre[4], hacc[4][Hh];
#pragma unroll
      for (int r = 0; r < 4; ++r) {
        pre[r] = acc[mt][nt][r] + basep[(size_t)(b0 + r) * Dn + d];
#pragma unroll
        for (int hh = 0; hh < Hh; ++hh) hacc[r][hh] = b1v[hh];
      }
#pragma unroll
      for (int s = 0; s < TAU; ++s) {
        float wv[Hh];
#pragma unroll
        for (int hh = 0; hh < Hh; ++hh) wv[hh] = w1[((15 - TAU + s) * Hh + hh) * Dn + d];
#pragma unroll
        for (int r = 0; r < 4; ++r) {
          float psv = hist[(size_t)s * BD + (size_t)(b0 + r) * Dn + d];
#pragma unroll
          for (int hh = 0; hh < Hh; ++hh) hacc[r][hh] = fmaf(psv, wv[hh], hacc[r][hh]);
        }
      }
      {
        float wv[Hh];
#pragma unroll
        for (int hh = 0; hh < Hh; ++hh) wv[hh] = w1[(15 * Hh + hh) * Dn + d];
#pragma unroll
        for (int r = 0; r < 4; ++r)
#pragma unroll
          for (int hh = 0; hh < Hh; ++hh) hacc[r][hh] = fmaf(pre[r], wv[hh], hacc[r][hh]);
      }
      u16x4 pack;
#pragma unroll
      for (int r = 0; r < 4; ++r) {
        histout[(size_t)(b0 + r) * Dn + d] = pre[r];
        float z = b2v;
#pragma unroll
        for (int hh = 0; hh < Hh; ++hh) z = fmaf(fmaxf(hacc[r][hh], 0.f), w2v[hh], z);
        unsigned short h_, l_; split2(z, h_, l_);
        zho[(size_t)(b0 + r) * Dn + d] = h_;
        zlo[(size_t)(b0 + r) * Dn + d] = l_;
        pack[r] = f2bf(z);
      }
      *(u16x4*)&zT[(size_t)d * Bsz + b0] = pack;
    }
}

// ---------------- tick 0: pre = base + q, NLM single term --------------------
__global__ __launch_bounds__(256)
void tick0_kernel(const float* __restrict__ basep, const float* __restrict__ q,
                  float* __restrict__ histout,
                  const float* __restrict__ w1, const float* __restrict__ b1,
                  const float* __restrict__ w2, const float* __restrict__ b2,
                  unsigned short* __restrict__ zho, unsigned short* __restrict__ zlo,
                  unsigned short* __restrict__ zT)
{
  int g = blockIdx.x * 256 + threadIdx.x;
  int b = g >> 8;
  int d0 = (g & 255) * 8;
#pragma unroll
  for (int k = 0; k < 8; ++k) {
    int d = d0 + k;
    float pre = basep[(size_t)b * Dn + d] + q[d];
    histout[(size_t)b * Dn + d] = pre;
    float z = b2[d];
#pragma unroll
    for (int hh = 0; hh < Hh; ++hh) {
      float h = fmaf(pre, w1[(15 * Hh + hh) * Dn + d], b1[hh * Dn + d]);
      z = fmaf(fmaxf(h, 0.f), w2[hh * Dn + d], z);
    }
    unsigned short h_, l_; split2(z, h_, l_);
    zho[(size_t)b * Dn + d] = h_;
    zlo[(size_t)b * Dn + d] = l_;
    zT[(size_t)d * Bsz + b] = f2bf(z);
  }
}

// ---------------- batched sync: S for all ticks, both sets -------------------
__global__ __launch_bounds__(512)
void sync_kernel(const unsigned short* __restrict__ zT,
                 const int* __restrict__ pairs0, const int* __restrict__ pairs1,
                 const float* __restrict__ decay0, const float* __restrict__ decay1,
                 unsigned short* __restrict__ Sh0, unsigned short* __restrict__ Sl0,
                 unsigned short* __restrict__ Sh1, unsigned short* __restrict__ Sl1)
{
  __shared__ float Ls[8][8][65];
  const int set = blockIdx.y;
  const int* pairs = set ? pairs1 : pairs0;
  const float* decay = set ? decay1 : decay0;
  unsigned short* Sh = set ? Sh1 : Sh0;
  unsigned short* Sl = set ? Sl1 : Sl0;
  const int tid = threadIdx.x;
  const int lb = tid & 63, pl = tid >> 6;
  const int p = blockIdx.x * 8 + pl;
  const int i = pairs[2 * p], j = pairs[2 * p + 1];
  const float r = expf(-fabsf(decay[p]));
  const int pb = tid & 7, bb2 = tid >> 3;
  for (int bb = 0; bb < 8; ++bb) {
    int b = bb * 64 + lb;
    float S = 0.f, St[8];
#pragma unroll
    for (int t = 0; t < 8; ++t) {
      float zi = bf2f(zT[(size_t)t * BD + (size_t)i * Bsz + b]);
      float zj = bf2f(zT[(size_t)t * BD + (size_t)j * Bsz + b]);
      S = fmaf(S, r, zi * zj);
      St[t] = S;
    }
#pragma unroll
    for (int t = 0; t < 8; ++t) Ls[pl][t][lb] = St[t];
    __syncthreads();
#pragma unroll
    for (int t = 0; t < 8; ++t) {
      float v = Ls[pb][t][bb2];
      unsigned short h_, l_; split2(v, h_, l_);
      size_t off = ((size_t)t * Bsz + bb * 64 + bb2) * Pn + blockIdx.x * 8 + pb;
      Sh[off] = h_; Sl[off] = l_;
    }
    __syncthreads();
  }
}

// ---------------- weight transpose + bf16x2 split: (K,N) -> h/l (N,K) --------
__global__ __launch_bounds__(256)
void transpose_split_kernel(const float* __restrict__ in, int ldin,
                            unsigned short* __restrict__ Th, unsigned short* __restrict__ Tl,
                            int K)
{
  __shared__ float T[64][65];
  int k0 = blockIdx.x * 64, n0 = blockIdx.y * 64;
  int tid = threadIdx.x;
  int r = tid >> 2, c0 = (tid & 3) * 16;
#pragma unroll
  for (int cc = 0; cc < 16; cc += 4) {
    float4 v = *(const float4*)(in + (size_t)(k0 + r) * ldin + n0 + c0 + cc);
    T[c0 + cc + 0][r] = v.x; T[c0 + cc + 1][r] = v.y;
    T[c0 + cc + 2][r] = v.z; T[c0 + cc + 3][r] = v.w;
  }
  __syncthreads();
  int n = tid >> 2, kc = (tid & 3) * 16;
#pragma unroll
  for (int kk = 0; kk < 16; ++kk) {
    float v = T[n][kc + kk];
    unsigned short h_, l_; split2(v, h_, l_);
    Th[(size_t)(n0 + n) * K + k0 + kc + kk] = h_;
    Tl[(size_t)(n0 + n) * K + k0 + kc + kk] = l_;
  }
}

// ---------------- elementwise split (x) --------------------------------------
__global__ __launch_bounds__(256)
void split_kernel(const float* __restrict__ x, unsigned short* __restrict__ xh,
                  unsigned short* __restrict__ xl, int n4)
{
  int i = blockIdx.x * 256 + threadIdx.x;
  if (i >= n4) return;
  float4 v = *(const float4*)(x + (size_t)i * 4);
  u16x4 h, l;
  unsigned short th, tl;
  split2(v.x, th, tl); h[0] = th; l[0] = tl;
  split2(v.y, th, tl); h[1] = th; l[1] = tl;
  split2(v.z, th, tl); h[2] = th; l[2] = tl;
  split2(v.w, th, tl); h[3] = th; l[3] = tl;
  *(u16x4*)(xh + (size_t)i * 4) = h;
  *(u16x4*)(xl + (size_t)i * 4) = l;
}

// ---------------- fp32 matvec: out = vec @ W (+bias) -------------------------
__global__ __launch_bounds__(256)
void matvec_kernel(const float* __restrict__ vec, const float* __restrict__ W,
                   const float* __restrict__ bias, float* __restrict__ out, int K, int N)
{
  __shared__ float red[16][17];
  const int tid = threadIdx.x;
  const int c = tid & 15, strip = tid >> 4;
  const int col = blockIdx.x * 16 + c;
  float acc = 0.f;
  for (int k = strip; k < K; k += 16)
    acc = fmaf(vec[k], W[(size_t)k * N + col], acc);
  red[strip][c] = acc;
  __syncthreads();
  if (strip == 0) {
    float s = bias ? bias[col] : 0.f;
#pragma unroll
    for (int i2 = 0; i2 < 16; ++i2) s += red[i2][c];
    out[col] = s;
  }
}

extern "C" void kernel_launch(void* const* d_in, const int* in_sizes, int n_in,
                              void* d_out, int out_size, void* d_ws, size_t ws_size,
                              hipStream_t stream) {
  const float* x      = (const float*)d_in[0];
  const float* W_in   = (const float*)d_in[1];
  const float* b_in   = (const float*)d_in[2];
  const float* z0     = (const float*)d_in[3];
  const float* W_syn  = (const float*)d_in[4];
  const float* b_syn  = (const float*)d_in[5];
  const float* w1     = (const float*)d_in[6];
  const float* b1     = (const float*)d_in[7];
  const float* w2     = (const float*)d_in[8];
  const float* b2     = (const float*)d_in[9];
  const float* decay_out = (const float*)d_in[10];
  const float* decay_act = (const float*)d_in[11];
  const float* W_out  = (const float*)d_in[12];
  const float* b_out  = (const float*)d_in[13];
  const float* W_act  = (const float*)d_in[14];
  const float* b_act  = (const float*)d_in[15];
  const int* pairs_out = (const int*)d_in[16];
  const int* pairs_act = (const int*)d_in[17];

  char* W = (char*)d_ws;
  auto alloc = [&](size_t bytes) { char* p = W; W += (bytes + 255) & ~255ull; return p; };
  unsigned short* WtTh = (unsigned short*)alloc((size_t)Dn * Dn * 2);
  unsigned short* WtTl = (unsigned short*)alloc((size_t)Dn * Dn * 2);
  unsigned short* WbTh = (unsigned short*)alloc((size_t)Dn * Dn * 2);
  unsigned short* WbTl = (unsigned short*)alloc((size_t)Dn * Dn * 2);
  unsigned short* WinTh = (unsigned short*)alloc((size_t)Dn * DIN * 2);
  unsigned short* WinTl = (unsigned short*)alloc((size_t)Dn * DIN * 2);
  unsigned short* WoTh = (unsigned short*)alloc((size_t)DOUT * Pn * 2);
  unsigned short* WoTl = (unsigned short*)alloc((size_t)DOUT * Pn * 2);
  unsigned short* WaTh = (unsigned short*)alloc((size_t)DOUT * Pn * 2);
  unsigned short* WaTl = (unsigned short*)alloc((size_t)DOUT * Pn * 2);
  unsigned short* xh = (unsigned short*)alloc((size_t)Bsz * DIN * 2);
  unsigned short* xl = (unsigned short*)alloc((size_t)Bsz * DIN * 2);
  unsigned short* fh = (unsigned short*)alloc((size_t)BD * 2);
  unsigned short* fl = (unsigned short*)alloc((size_t)BD * 2);
  float* q    = (float*)alloc(Dn * 4);
  float* bb   = (float*)alloc(Dn * 4);
  float* base = (float*)alloc((size_t)BD * 4);
  float* hist = (float*)alloc((size_t)TT * BD * 4);
  unsigned short* zbh[2], *zbl[2];
  zbh[0] = (unsigned short*)alloc((size_t)BD * 2);
  zbl[0] = (unsigned short*)alloc((size_t)BD * 2);
  zbh[1] = (unsigned short*)alloc((size_t)BD * 2);
  zbl[1] = (unsigned short*)alloc((size_t)BD * 2);
  unsigned short* zT = (unsigned short*)alloc((size_t)TT * BD * 2);
  // S buffers alias the (dead-after-base-GEMM) WbT region: 4MB each
  unsigned short* Sh0 = WbTh;
  unsigned short* Sl0 = WbTh + (size_t)TT * Bsz * Pn;
  unsigned short* Sh1 = WbTl;
  unsigned short* Sl1 = WbTl + (size_t)TT * Bsz * Pn;

  float* outy = (float*)d_out;
  float* outq = outy + (size_t)Bsz * TT * DOUT;

  dim3 blk(256);
  // weight prep
  transpose_split_kernel<<<dim3(32, 32), blk, 0, stream>>>(W_syn, Dn, WtTh, WtTl, Dn);
  transpose_split_kernel<<<dim3(32, 32), blk, 0, stream>>>(W_syn + (size_t)Dn * Dn, Dn, WbTh, WbTl, Dn);
  transpose_split_kernel<<<dim3(8, 32), blk, 0, stream>>>(W_in, Dn, WinTh, WinTl, DIN);
  transpose_split_kernel<<<dim3(8, 8), blk, 0, stream>>>(W_out, DOUT, WoTh, WoTl, Pn);
  transpose_split_kernel<<<dim3(8, 8), blk, 0, stream>>>(W_act, DOUT, WaTh, WaTl, Pn);
  split_kernel<<<dim3(Bsz * DIN / 1024), blk, 0, stream>>>(x, xh, xl, Bsz * DIN / 4);
  matvec_kernel<<<dim3(Dn / 16), blk, 0, stream>>>(z0, W_syn, nullptr, q, Dn, Dn);
  matvec_kernel<<<dim3(Dn / 16), blk, 0, stream>>>(b_in, W_syn + (size_t)Dn * Dn, b_syn, bb, Dn, Dn);
  // feats' = x @ W_in (split output only)
  mfma_gemm<0><<<dim3(256), blk, 0, stream>>>(xh, xl, WinTh, WinTl, nullptr, nullptr, fh, fl,
                                              Bsz, Dn, DIN, 8, 32);
  // base = feats' @ W_syn_bot + (b_in @ W_syn_bot + b_syn)
  mfma_gemm<1><<<dim3(256), blk, 0, stream>>>(fh, fl, WbTh, WbTl, bb, base, nullptr, nullptr,
                                              Bsz, Dn, Dn, 8, 32);
  // tick 0
  tick0_kernel<<<dim3(512), blk, 0, stream>>>(base, q, hist, w1, b1, w2, b2,
                                              zbh[0], zbl[0], zT);
  // ticks 1..7
  for (int tau = 1; tau < TT; ++tau) {
    const unsigned short* zih = zbh[(tau + 1) & 1];
    const unsigned short* zil = zbl[(tau + 1) & 1];
    unsigned short* zoh = zbh[tau & 1];
    unsigned short* zol = zbl[tau & 1];
    float* ho = hist + (size_t)tau * BD;
    unsigned short* zTo = zT + (size_t)tau * BD;
    switch (tau) {
      case 1: tick_mfma<1><<<dim3(256), blk, 0, stream>>>(zih, zil, WtTh, WtTl, base, hist, ho, w1, b1, w2, b2, zoh, zol, zTo); break;
      case 2: tick_mfma<2><<<dim3(256), blk, 0, stream>>>(zih, zil, WtTh, WtTl, base, hist, ho, w1, b1, w2, b2, zoh, zol, zTo); break;
      case 3: tick_mfma<3><<<dim3(256), blk, 0, stream>>>(zih, zil, WtTh, WtTl, base, hist, ho, w1, b1, w2, b2, zoh, zol, zTo); break;
      case 4: tick_mfma<4><<<dim3(256), blk, 0, stream>>>(zih, zil, WtTh, WtTl, base, hist, ho, w1, b1, w2, b2, zoh, zol, zTo); break;
      case 5: tick_mfma<5><<<dim3(256), blk, 0, stream>>>(zih, zil, WtTh, WtTl, base, hist, ho, w1, b1, w2, b2, zoh, zol, zTo); break;
      case 6: tick_mfma<6><<<dim3(256), blk, 0, stream>>>(zih, zil, WtTh, WtTl, base, hist, ho, w1, b1, w2, b2, zoh, zol, zTo); break;
      case 7: tick_mfma<7><<<dim3(256), blk, 0, stream>>>(zih, zil, WtTh, WtTl, base, hist, ho, w1, b1, w2, b2, zoh, zol, zTo); break;
    }
  }
  // batched sync for both sets
  sync_kernel<<<dim3(Pn / 8, 2), dim3(512), 0, stream>>>(zT, pairs_out, pairs_act,
                                                         decay_out, decay_act,
                                                         Sh0, Sl0, Sh1, Sl1);
  // output GEMMs over all (t, b) rows
  mfma_gemm<2><<<dim3(512), blk, 0, stream>>>(Sh0, Sl0, WoTh, WoTl, b_out, outy, nullptr, nullptr,
                                              TT * Bsz, DOUT, Pn, 64, 8);
  mfma_gemm<2><<<dim3(512), blk, 0, stream>>>(Sh1, Sl1, WaTh, WaTl, b_act, outq, nullptr, nullptr,
                                              TT * Bsz, DOUT, Pn, 64, 8);
}

// Round 4
// 676.234 us; speedup vs baseline: 2.2538x; 1.0266x over previous
//
#include <hip/hip_runtime.h>
#include <math.h>

#define Bsz 512
#define TT 8
#define Dn 2048
#define DIN 512
#define Hh 4
#define Pn 512
#define DOUT 512
#define BD (Bsz*Dn)

typedef __attribute__((ext_vector_type(8))) short s16x8;
typedef __attribute__((ext_vector_type(4))) float f32x4;
typedef __attribute__((ext_vector_type(4))) unsigned short u16x4;

__device__ __forceinline__ unsigned short f2bf(float f) {
  unsigned int u = __float_as_uint(f);
  unsigned int r = (u + 0x7fffu + ((u >> 16) & 1u)) >> 16;
  return (unsigned short)r;
}
__device__ __forceinline__ float bf2f(unsigned short h) {
  return __uint_as_float(((unsigned int)h) << 16);
}
__device__ __forceinline__ void split2(float x, unsigned short& h, unsigned short& l) {
  h = f2bf(x);
  float r = x - bf2f(h);
  l = f2bf(r);
}

// ---------------- shared MFMA GEMM core ----------------
// A (M,K) as Ah/Al bf16 row-major; B as BT h/l (N,K) row-major.
// 32x64 block tile, BK=32, 4 waves of 16x32, double-buffered swizzled LDS.
// Grid sized 2 blocks/CU for latency hiding (r3 fix: 64x64 was 1 block/CU,
// occupancy 10%, MfmaUtil 7% -> latency-bound).
__device__ __forceinline__ void gemm_core(
    const unsigned short* __restrict__ Ah, const unsigned short* __restrict__ Al,
    const unsigned short* __restrict__ BTh, const unsigned short* __restrict__ BTl,
    int K, long arow0, long brow0,
    unsigned short As[2][32][64], unsigned short Bs[2][64][64],
    f32x4 acc[2])
{
  const int tid = threadIdx.x;
  // A staging: 256 vectors (32 rows x 4 kgroups x {h,l}), one per thread
  const int ar = tid & 31, akg = (tid >> 5) & 3, apart = tid >> 7;
  const unsigned short* Asrc = (apart ? Al : Ah) + (size_t)(arow0 + ar) * K + akg * 8;
  const int aslot = ((apart * 4 + akg) ^ (ar & 7)) * 8;
  // B staging: 512 vectors (64 rows x 4 kgroups x {h,l}), two per thread
  const int br = tid & 63, bkg = (tid >> 6) & 3;
  const unsigned short* Bsrc0 = BTh + (size_t)(brow0 + br) * K + bkg * 8;
  const unsigned short* Bsrc1 = BTl + (size_t)(brow0 + br) * K + bkg * 8;
  const int bslot0 = (bkg ^ (br & 7)) * 8;
  const int bslot1 = ((bkg + 4) ^ (br & 7)) * 8;

  {
    s16x8 va  = *(const s16x8*)Asrc;
    s16x8 vb0 = *(const s16x8*)Bsrc0;
    s16x8 vb1 = *(const s16x8*)Bsrc1;
    *(s16x8*)&As[0][ar][aslot]  = va;
    *(s16x8*)&Bs[0][br][bslot0] = vb0;
    *(s16x8*)&Bs[0][br][bslot1] = vb1;
  }
  __syncthreads();

  // fragment addressing
  const int lane = tid & 63, wave = tid >> 6;
  const int wm = (wave & 1) * 16, wn = (wave >> 1) * 32;
  const int lm = lane & 15, kg4 = lane >> 4;   // 0..3
  const int arow = wm + lm;
  const int aoH = (kg4 ^ (arow & 7)) * 8;
  const int aoL = ((kg4 + 4) ^ (arow & 7)) * 8;
  int brr[2], boH[2], boL[2];
#pragma unroll
  for (int nt = 0; nt < 2; ++nt) {
    int r = wn + nt * 16 + lm;
    brr[nt] = r;
    boH[nt] = (kg4 ^ (r & 7)) * 8;
    boL[nt] = ((kg4 + 4) ^ (r & 7)) * 8;
  }

  const int nk = K >> 5;
  for (int ks = 0; ks < nk; ++ks) {
    const int cur = ks & 1;
    s16x8 na, nb0, nb1;
    if (ks + 1 < nk) {
      size_t o = (size_t)(ks + 1) * 32;
      na  = *(const s16x8*)(Asrc + o);
      nb0 = *(const s16x8*)(Bsrc0 + o);
      nb1 = *(const s16x8*)(Bsrc1 + o);
    }
    s16x8 fa_h = *(const s16x8*)&As[cur][arow][aoH];
    s16x8 fa_l = *(const s16x8*)&As[cur][arow][aoL];
    s16x8 fb_h[2], fb_l[2];
#pragma unroll
    for (int nt = 0; nt < 2; ++nt) {
      fb_h[nt] = *(const s16x8*)&Bs[cur][brr[nt]][boH[nt]];
      fb_l[nt] = *(const s16x8*)&Bs[cur][brr[nt]][boL[nt]];
    }
#pragma unroll
    for (int nt = 0; nt < 2; ++nt) {
      acc[nt] = __builtin_amdgcn_mfma_f32_16x16x32_bf16(fa_h, fb_h[nt], acc[nt], 0, 0, 0);
      acc[nt] = __builtin_amdgcn_mfma_f32_16x16x32_bf16(fa_h, fb_l[nt], acc[nt], 0, 0, 0);
      acc[nt] = __builtin_amdgcn_mfma_f32_16x16x32_bf16(fa_l, fb_h[nt], acc[nt], 0, 0, 0);
    }
    if (ks + 1 < nk) {
      const int nxt = cur ^ 1;
      *(s16x8*)&As[nxt][ar][aslot]  = na;
      *(s16x8*)&Bs[nxt][br][bslot0] = nb0;
      *(s16x8*)&Bs[nxt][br][bslot1] = nb1;
    }
    __syncthreads();
  }
}

// MODE 0: write split bf16 (Ch/Cl). MODE 1: write fp32 C + bias. MODE 2: out scatter (b,t,n) + bias.
template<int MODE>
__global__ __launch_bounds__(256)
void mfma_gemm(const unsigned short* __restrict__ Ah, const unsigned short* __restrict__ Al,
               const unsigned short* __restrict__ BTh, const unsigned short* __restrict__ BTl,
               const float* __restrict__ bias, float* __restrict__ Cf,
               unsigned short* __restrict__ Ch, unsigned short* __restrict__ Cl,
               int M, int N, int K, int gm, int gn)
{
  __shared__ unsigned short As[2][32][64];
  __shared__ unsigned short Bs[2][64][64];
  int bid = blockIdx.x;
  int xcd = bid & 7, w = bid >> 3;
  int bmi = w % gm, bni = xcd * (gn >> 3) + w / gm;
  long bm = (long)bmi * 32, bn = (long)bni * 64;
  f32x4 acc[2];
  acc[0] = (f32x4)0.f; acc[1] = (f32x4)0.f;
  gemm_core(Ah, Al, BTh, BTl, K, bm, bn, As, Bs, acc);

  const int tid = threadIdx.x, lane = tid & 63, wave = tid >> 6;
  const int wm = (wave & 1) * 16, wn = (wave >> 1) * 32;
#pragma unroll
  for (int nt = 0; nt < 2; ++nt) {
    int n = (int)bn + wn + nt * 16 + (lane & 15);
    long r0 = bm + wm + (lane >> 4) * 4;
    float bv = (MODE != 0) ? bias[n] : 0.f;
#pragma unroll
    for (int r = 0; r < 4; ++r) {
      float v = acc[nt][r] + bv;
      long R = r0 + r;
      if (MODE == 0) {
        unsigned short h_, l_; split2(v, h_, l_);
        Ch[R * N + n] = h_; Cl[R * N + n] = l_;
      } else if (MODE == 1) {
        Cf[R * N + n] = v;
      } else {
        long t = R >> 9, b = R & 511;
        Cf[(b * TT + t) * N + n] = v;
      }
    }
  }
}

// ---------------- tick kernel (tau >= 1): GEMM + base + NLM epilogue ----------
template<int TAU>
__global__ __launch_bounds__(256)
void tick_mfma(const unsigned short* __restrict__ zh, const unsigned short* __restrict__ zl,
               const unsigned short* __restrict__ WTh, const unsigned short* __restrict__ WTl,
               const float* __restrict__ basep, const float* __restrict__ hist,
               float* __restrict__ histout,
               const float* __restrict__ w1, const float* __restrict__ b1,
               const float* __restrict__ w2, const float* __restrict__ b2,
               unsigned short* __restrict__ zho, unsigned short* __restrict__ zlo,
               unsigned short* __restrict__ zT)
{
  __shared__ unsigned short As[2][32][64];
  __shared__ unsigned short Bs[2][64][64];
  int bid = blockIdx.x;
  int xcd = bid & 7, w = bid >> 3;
  int bmi = w % 16, bni = xcd * 4 + w / 16;
  long bm = (long)bmi * 32, bn = (long)bni * 64;
  f32x4 acc[2];
  acc[0] = (f32x4)0.f; acc[1] = (f32x4)0.f;
  gemm_core(zh, zl, WTh, WTl, Dn, bm, bn, As, Bs, acc);

  const int tid = threadIdx.x, lane = tid & 63, wave = tid >> 6;
  const int wm = (wave & 1) * 16, wn = (wave >> 1) * 32;
#pragma unroll
  for (int nt = 0; nt < 2; ++nt) {
    const int d = (int)bn + wn + nt * 16 + (lane & 15);
    const int b0 = (int)bm + wm + (lane >> 4) * 4;
    float w2v[Hh], b1v[Hh];
#pragma unroll
    for (int hh = 0; hh < Hh; ++hh) {
      w2v[hh] = w2[hh * Dn + d];
      b1v[hh] = b1[hh * Dn + d];
    }
    const float b2v = b2[d];
    float pre[4], hacc[4][Hh];
#pragma unroll
    for (int r = 0; r < 4; ++r) {
      pre[r] = acc[nt][r] + basep[(size_t)(b0 + r) * Dn + d];
#pragma unroll
      for (int hh = 0; hh < Hh; ++hh) hacc[r][hh] = b1v[hh];
    }
#pragma unroll
    for (int s = 0; s < TAU; ++s) {
      float wv[Hh];
#pragma unroll
      for (int hh = 0; hh < Hh; ++hh) wv[hh] = w1[((15 - TAU + s) * Hh + hh) * Dn + d];
#pragma unroll
      for (int r = 0; r < 4; ++r) {
        float psv = hist[(size_t)s * BD + (size_t)(b0 + r) * Dn + d];
#pragma unroll
        for (int hh = 0; hh < Hh; ++hh) hacc[r][hh] = fmaf(psv, wv[hh], hacc[r][hh]);
      }
    }
    {
      float wv[Hh];
#pragma unroll
      for (int hh = 0; hh < Hh; ++hh) wv[hh] = w1[(15 * Hh + hh) * Dn + d];
#pragma unroll
      for (int r = 0; r < 4; ++r)
#pragma unroll
        for (int hh = 0; hh < Hh; ++hh) hacc[r][hh] = fmaf(pre[r], wv[hh], hacc[r][hh]);
    }
    u16x4 pack;
#pragma unroll
    for (int r = 0; r < 4; ++r) {
      histout[(size_t)(b0 + r) * Dn + d] = pre[r];
      float z = b2v;
#pragma unroll
      for (int hh = 0; hh < Hh; ++hh) z = fmaf(fmaxf(hacc[r][hh], 0.f), w2v[hh], z);
      unsigned short h_, l_; split2(z, h_, l_);
      zho[(size_t)(b0 + r) * Dn + d] = h_;
      zlo[(size_t)(b0 + r) * Dn + d] = l_;
      pack[r] = f2bf(z);
    }
    *(u16x4*)&zT[(size_t)d * Bsz + b0] = pack;
  }
}

// ---------------- tick 0: pre = base + q, NLM single term --------------------
__global__ __launch_bounds__(256)
void tick0_kernel(const float* __restrict__ basep, const float* __restrict__ q,
                  float* __restrict__ histout,
                  const float* __restrict__ w1, const float* __restrict__ b1,
                  const float* __restrict__ w2, const float* __restrict__ b2,
                  unsigned short* __restrict__ zho, unsigned short* __restrict__ zlo,
                  unsigned short* __restrict__ zT)
{
  int g = blockIdx.x * 256 + threadIdx.x;
  int b = g >> 8;
  int d0 = (g & 255) * 8;
#pragma unroll
  for (int k = 0; k < 8; ++k) {
    int d = d0 + k;
    float pre = basep[(size_t)b * Dn + d] + q[d];
    histout[(size_t)b * Dn + d] = pre;
    float z = b2[d];
#pragma unroll
    for (int hh = 0; hh < Hh; ++hh) {
      float h = fmaf(pre, w1[(15 * Hh + hh) * Dn + d], b1[hh * Dn + d]);
      z = fmaf(fmaxf(h, 0.f), w2[hh * Dn + d], z);
    }
    unsigned short h_, l_; split2(z, h_, l_);
    zho[(size_t)b * Dn + d] = h_;
    zlo[(size_t)b * Dn + d] = l_;
    zT[(size_t)d * Bsz + b] = f2bf(z);
  }
}

// ---------------- batched sync: S for all ticks, both sets -------------------
__global__ __launch_bounds__(512)
void sync_kernel(const unsigned short* __restrict__ zT,
                 const int* __restrict__ pairs0, const int* __restrict__ pairs1,
                 const float* __restrict__ decay0, const float* __restrict__ decay1,
                 unsigned short* __restrict__ Sh0, unsigned short* __restrict__ Sl0,
                 unsigned short* __restrict__ Sh1, unsigned short* __restrict__ Sl1)
{
  __shared__ float Ls[8][8][65];
  const int set = blockIdx.y;
  const int* pairs = set ? pairs1 : pairs0;
  const float* decay = set ? decay1 : decay0;
  unsigned short* Sh = set ? Sh1 : Sh0;
  unsigned short* Sl = set ? Sl1 : Sl0;
  const int tid = threadIdx.x;
  const int lb = tid & 63, pl = tid >> 6;
  const int p = blockIdx.x * 8 + pl;
  const int i = pairs[2 * p], j = pairs[2 * p + 1];
  const float r = expf(-fabsf(decay[p]));
  const int pb = tid & 7, bb2 = tid >> 3;
  for (int bb = 0; bb < 8; ++bb) {
    int b = bb * 64 + lb;
    float S = 0.f, St[8];
#pragma unroll
    for (int t = 0; t < 8; ++t) {
      float zi = bf2f(zT[(size_t)t * BD + (size_t)i * Bsz + b]);
      float zj = bf2f(zT[(size_t)t * BD + (size_t)j * Bsz + b]);
      S = fmaf(S, r, zi * zj);
      St[t] = S;
    }
#pragma unroll
    for (int t = 0; t < 8; ++t) Ls[pl][t][lb] = St[t];
    __syncthreads();
#pragma unroll
    for (int t = 0; t < 8; ++t) {
      float v = Ls[pb][t][bb2];
      unsigned short h_, l_; split2(v, h_, l_);
      size_t off = ((size_t)t * Bsz + bb * 64 + bb2) * Pn + blockIdx.x * 8 + pb;
      Sh[off] = h_; Sl[off] = l_;
    }
    __syncthreads();
  }
}

// ---------------- weight transpose + bf16x2 split: (K,N) -> h/l (N,K) --------
__global__ __launch_bounds__(256)
void transpose_split_kernel(const float* __restrict__ in, int ldin,
                            unsigned short* __restrict__ Th, unsigned short* __restrict__ Tl,
                            int K)
{
  __shared__ float T[64][65];
  int k0 = blockIdx.x * 64, n0 = blockIdx.y * 64;
  int tid = threadIdx.x;
  int r = tid >> 2, c0 = (tid & 3) * 16;
#pragma unroll
  for (int cc = 0; cc < 16; cc += 4) {
    float4 v = *(const float4*)(in + (size_t)(k0 + r) * ldin + n0 + c0 + cc);
    T[c0 + cc + 0][r] = v.x; T[c0 + cc + 1][r] = v.y;
    T[c0 + cc + 2][r] = v.z; T[c0 + cc + 3][r] = v.w;
  }
  __syncthreads();
  int n = tid >> 2, kc = (tid & 3) * 16;
#pragma unroll
  for (int kk = 0; kk < 16; ++kk) {
    float v = T[n][kc + kk];
    unsigned short h_, l_; split2(v, h_, l_);
    Th[(size_t)(n0 + n) * K + k0 + kc + kk] = h_;
    Tl[(size_t)(n0 + n) * K + k0 + kc + kk] = l_;
  }
}

// ---------------- elementwise split (x) --------------------------------------
__global__ __launch_bounds__(256)
void split_kernel(const float* __restrict__ x, unsigned short* __restrict__ xh,
                  unsigned short* __restrict__ xl, int n4)
{
  int i = blockIdx.x * 256 + threadIdx.x;
  if (i >= n4) return;
  float4 v = *(const float4*)(x + (size_t)i * 4);
  u16x4 h, l;
  unsigned short th, tl;
  split2(v.x, th, tl); h[0] = th; l[0] = tl;
  split2(v.y, th, tl); h[1] = th; l[1] = tl;
  split2(v.z, th, tl); h[2] = th; l[2] = tl;
  split2(v.w, th, tl); h[3] = th; l[3] = tl;
  *(u16x4*)(xh + (size_t)i * 4) = h;
  *(u16x4*)(xl + (size_t)i * 4) = l;
}

// ---------------- fp32 matvec: out = vec @ W (+bias) -------------------------
__global__ __launch_bounds__(256)
void matvec_kernel(const float* __restrict__ vec, const float* __restrict__ W,
                   const float* __restrict__ bias, float* __restrict__ out, int K, int N)
{
  __shared__ float red[16][17];
  const int tid = threadIdx.x;
  const int c = tid & 15, strip = tid >> 4;
  const int col = blockIdx.x * 16 + c;
  float acc = 0.f;
  for (int k = strip; k < K; k += 16)
    acc = fmaf(vec[k], W[(size_t)k * N + col], acc);
  red[strip][c] = acc;
  __syncthreads();
  if (strip == 0) {
    float s = bias ? bias[col] : 0.f;
#pragma unroll
    for (int i2 = 0; i2 < 16; ++i2) s += red[i2][c];
    out[col] = s;
  }
}

extern "C" void kernel_launch(void* const* d_in, const int* in_sizes, int n_in,
                              void* d_out, int out_size, void* d_ws, size_t ws_size,
                              hipStream_t stream) {
  const float* x      = (const float*)d_in[0];
  const float* W_in   = (const float*)d_in[1];
  const float* b_in   = (const float*)d_in[2];
  const float* z0     = (const float*)d_in[3];
  const float* W_syn  = (const float*)d_in[4];
  const float* b_syn  = (const float*)d_in[5];
  const float* w1     = (const float*)d_in[6];
  const float* b1     = (const float*)d_in[7];
  const float* w2     = (const float*)d_in[8];
  const float* b2     = (const float*)d_in[9];
  const float* decay_out = (const float*)d_in[10];
  const float* decay_act = (const float*)d_in[11];
  const float* W_out  = (const float*)d_in[12];
  const float* b_out  = (const float*)d_in[13];
  const float* W_act  = (const float*)d_in[14];
  const float* b_act  = (const float*)d_in[15];
  const int* pairs_out = (const int*)d_in[16];
  const int* pairs_act = (const int*)d_in[17];

  char* W = (char*)d_ws;
  auto alloc = [&](size_t bytes) { char* p = W; W += (bytes + 255) & ~255ull; return p; };
  unsigned short* WtTh = (unsigned short*)alloc((size_t)Dn * Dn * 2);
  unsigned short* WtTl = (unsigned short*)alloc((size_t)Dn * Dn * 2);
  unsigned short* WbTh = (unsigned short*)alloc((size_t)Dn * Dn * 2);
  unsigned short* WbTl = (unsigned short*)alloc((size_t)Dn * Dn * 2);
  unsigned short* WinTh = (unsigned short*)alloc((size_t)Dn * DIN * 2);
  unsigned short* WinTl = (unsigned short*)alloc((size_t)Dn * DIN * 2);
  unsigned short* WoTh = (unsigned short*)alloc((size_t)DOUT * Pn * 2);
  unsigned short* WoTl = (unsigned short*)alloc((size_t)DOUT * Pn * 2);
  unsigned short* WaTh = (unsigned short*)alloc((size_t)DOUT * Pn * 2);
  unsigned short* WaTl = (unsigned short*)alloc((size_t)DOUT * Pn * 2);
  unsigned short* xh = (unsigned short*)alloc((size_t)Bsz * DIN * 2);
  unsigned short* xl = (unsigned short*)alloc((size_t)Bsz * DIN * 2);
  unsigned short* fh = (unsigned short*)alloc((size_t)BD * 2);
  unsigned short* fl = (unsigned short*)alloc((size_t)BD * 2);
  float* q    = (float*)alloc(Dn * 4);
  float* bb   = (float*)alloc(Dn * 4);
  float* base = (float*)alloc((size_t)BD * 4);
  float* hist = (float*)alloc((size_t)TT * BD * 4);
  unsigned short* zbh[2], *zbl[2];
  zbh[0] = (unsigned short*)alloc((size_t)BD * 2);
  zbl[0] = (unsigned short*)alloc((size_t)BD * 2);
  zbh[1] = (unsigned short*)alloc((size_t)BD * 2);
  zbl[1] = (unsigned short*)alloc((size_t)BD * 2);
  unsigned short* zT = (unsigned short*)alloc((size_t)TT * BD * 2);
  // S buffers alias the (dead-after-base-GEMM) WbT region: 4MB each
  unsigned short* Sh0 = WbTh;
  unsigned short* Sl0 = WbTh + (size_t)TT * Bsz * Pn;
  unsigned short* Sh1 = WbTl;
  unsigned short* Sl1 = WbTl + (size_t)TT * Bsz * Pn;

  float* outy = (float*)d_out;
  float* outq = outy + (size_t)Bsz * TT * DOUT;

  dim3 blk(256);
  // weight prep
  transpose_split_kernel<<<dim3(32, 32), blk, 0, stream>>>(W_syn, Dn, WtTh, WtTl, Dn);
  transpose_split_kernel<<<dim3(32, 32), blk, 0, stream>>>(W_syn + (size_t)Dn * Dn, Dn, WbTh, WbTl, Dn);
  transpose_split_kernel<<<dim3(8, 32), blk, 0, stream>>>(W_in, Dn, WinTh, WinTl, DIN);
  transpose_split_kernel<<<dim3(8, 8), blk, 0, stream>>>(W_out, DOUT, WoTh, WoTl, Pn);
  transpose_split_kernel<<<dim3(8, 8), blk, 0, stream>>>(W_act, DOUT, WaTh, WaTl, Pn);
  split_kernel<<<dim3(Bsz * DIN / 1024), blk, 0, stream>>>(x, xh, xl, Bsz * DIN / 4);
  matvec_kernel<<<dim3(Dn / 16), blk, 0, stream>>>(z0, W_syn, nullptr, q, Dn, Dn);
  matvec_kernel<<<dim3(Dn / 16), blk, 0, stream>>>(b_in, W_syn + (size_t)Dn * Dn, b_syn, bb, Dn, Dn);
  // feats' = x @ W_in (split output only)
  mfma_gemm<0><<<dim3(512), blk, 0, stream>>>(xh, xl, WinTh, WinTl, nullptr, nullptr, fh, fl,
                                              Bsz, Dn, DIN, 16, 32);
  // base = feats' @ W_syn_bot + (b_in @ W_syn_bot + b_syn)
  mfma_gemm<1><<<dim3(512), blk, 0, stream>>>(fh, fl, WbTh, WbTl, bb, base, nullptr, nullptr,
                                              Bsz, Dn, Dn, 16, 32);
  // tick 0
  tick0_kernel<<<dim3(512), blk, 0, stream>>>(base, q, hist, w1, b1, w2, b2,
                                              zbh[0], zbl[0], zT);
  // ticks 1..7
  for (int tau = 1; tau < TT; ++tau) {
    const unsigned short* zih = zbh[(tau + 1) & 1];
    const unsigned short* zil = zbl[(tau + 1) & 1];
    unsigned short* zoh = zbh[tau & 1];
    unsigned short* zol = zbl[tau & 1];
    float* ho = hist + (size_t)tau * BD;
    unsigned short* zTo = zT + (size_t)tau * BD;
    switch (tau) {
      case 1: tick_mfma<1><<<dim3(512), blk, 0, stream>>>(zih, zil, WtTh, WtTl, base, hist, ho, w1, b1, w2, b2, zoh, zol, zTo); break;
      case 2: tick_mfma<2><<<dim3(512), blk, 0, stream>>>(zih, zil, WtTh, WtTl, base, hist, ho, w1, b1, w2, b2, zoh, zol, zTo); break;
      case 3: tick_mfma<3><<<dim3(512), blk, 0, stream>>>(zih, zil, WtTh, WtTl, base, hist, ho, w1, b1, w2, b2, zoh, zol, zTo); break;
      case 4: tick_mfma<4><<<dim3(512), blk, 0, stream>>>(zih, zil, WtTh, WtTl, base, hist, ho, w1, b1, w2, b2, zoh, zol, zTo); break;
      case 5: tick_mfma<5><<<dim3(512), blk, 0, stream>>>(zih, zil, WtTh, WtTl, base, hist, ho, w1, b1, w2, b2, zoh, zol, zTo); break;
      case 6: tick_mfma<6><<<dim3(512), blk, 0, stream>>>(zih, zil, WtTh, WtTl, base, hist, ho, w1, b1, w2, b2, zoh, zol, zTo); break;
      case 7: tick_mfma<7><<<dim3(512), blk, 0, stream>>>(zih, zil, WtTh, WtTl, base, hist, ho, w1, b1, w2, b2, zoh, zol, zTo); break;
    }
  }
  // batched sync for both sets
  sync_kernel<<<dim3(Pn / 8, 2), dim3(512), 0, stream>>>(zT, pairs_out, pairs_act,
                                                         decay_out, decay_act,
                                                         Sh0, Sl0, Sh1, Sl1);
  // output GEMMs over all (t, b) rows
  mfma_gemm<2><<<dim3(1024), blk, 0, stream>>>(Sh0, Sl0, WoTh, WoTl, b_out, outy, nullptr, nullptr,
                                               TT * Bsz, DOUT, Pn, 128, 8);
  mfma_gemm<2><<<dim3(1024), blk, 0, stream>>>(Sh1, Sl1, WaTh, WaTl, b_act, outq, nullptr, nullptr,
                                               TT * Bsz, DOUT, Pn, 128, 8);
}